// Round 1
// baseline (2394.506 us; speedup 1.0000x reference)
//
#include <hip/hip_runtime.h>

#ifndef __HIP_DEVICE_COMPILE__
#include <cstring>
#endif

// ---------------- helpers ----------------

__device__ __forceinline__ unsigned fmap(float f) {
    unsigned u = __float_as_uint(f);
    return (u >> 31) ? ~u : (u | 0x80000000u);
}
__device__ __forceinline__ float funmap(unsigned m) {
    return __uint_as_float((m >> 31) ? (m ^ 0x80000000u) : ~m);
}

// ---------------- kernels ----------------

// H[r][j] = sum_k X[r][k] * W[k][j];  sc_s[r] = H[r].a_s;  sc_d[r] = H[r].a_d
template<int K>
__global__ void gat_gemm_kernel(const float* __restrict__ X, const float* __restrict__ W,
                                const float* __restrict__ a_s, const float* __restrict__ a_d,
                                float* __restrict__ H, float* __restrict__ sc_s,
                                float* __restrict__ sc_d, int nrows) {
    __shared__ float Wl[K * 64];
    __shared__ float As[64];
    __shared__ float Ad[64];
    for (int i = threadIdx.x; i < K * 64; i += blockDim.x) Wl[i] = W[i];
    if (threadIdx.x < 64) {
        As[threadIdx.x] = a_s[threadIdx.x];
        Ad[threadIdx.x] = a_d[threadIdx.x];
    }
    __syncthreads();

    const int lane = threadIdx.x & 63;
    const int wave = threadIdx.x >> 6;
    const int wpb  = blockDim.x >> 6;
    const int gw   = blockIdx.x * wpb + wave;
    const int nw   = gridDim.x * wpb;

    for (int r = gw; r < nrows; r += nw) {
        const float* xr = X + (size_t)r * K;
        float acc = 0.f;
#pragma unroll
        for (int k = 0; k < K; k += 4) {
            float4 xv = *reinterpret_cast<const float4*>(xr + k);
            acc += xv.x * Wl[(k + 0) * 64 + lane];
            acc += xv.y * Wl[(k + 1) * 64 + lane];
            acc += xv.z * Wl[(k + 2) * 64 + lane];
            acc += xv.w * Wl[(k + 3) * 64 + lane];
        }
        H[(size_t)r * 64 + lane] = acc;
        float ps = acc * As[lane];
        float pd = acc * Ad[lane];
#pragma unroll
        for (int off = 32; off; off >>= 1) {
            ps += __shfl_down(ps, off);
            pd += __shfl_down(pd, off);
        }
        if (lane == 0) {
            sc_s[r] = ps;
            sc_d[r] = pd;
        }
    }
}

// pass A: e = leaky_relu(sc_s[src] + sc_d[dst]); store e; segment-max into emax_u (monotone uint)
__global__ void edge_max_kernel(const int* __restrict__ ei, int E, int N,
                                const float* __restrict__ sc_s, const float* __restrict__ sc_d,
                                float* __restrict__ e_out, unsigned* __restrict__ emax_u) {
    int idx = blockIdx.x * blockDim.x + threadIdx.x;
    const int EE = E + N;
    const int stride = gridDim.x * blockDim.x;
    for (; idx < EE; idx += stride) {
        int s, d;
        if (idx < E) { s = ei[idx]; d = ei[E + idx]; }
        else         { s = d = idx - E; }
        float e = sc_s[s] + sc_d[d];
        e = e > 0.f ? e : 0.2f * e;
        e_out[idx] = e;
        atomicMax(&emax_u[d], fmap(e));
    }
}

// pass B: ex = exp(e - emax[dst]); store ex in place; denom[dst] += ex
__global__ void edge_exp_kernel(const int* __restrict__ ei, int E, int N,
                                float* __restrict__ e_inout, const unsigned* __restrict__ emax_u,
                                float* __restrict__ denom) {
    int idx = blockIdx.x * blockDim.x + threadIdx.x;
    const int EE = E + N;
    const int stride = gridDim.x * blockDim.x;
    for (; idx < EE; idx += stride) {
        int d = (idx < E) ? ei[E + idx] : (idx - E);
        float m = funmap(emax_u[d]);
        float ex = __expf(e_inout[idx] - m);
        e_inout[idx] = ex;
        unsafeAtomicAdd(&denom[d], ex);
    }
}

// pass C: out[dst][j] += h[src][j] * (ex / denom[dst]) — one wave per edge
__global__ void edge_agg_kernel(const int* __restrict__ ei, int E, int N,
                                const float* __restrict__ ex, const float* __restrict__ denom,
                                const float* __restrict__ H, float* __restrict__ OutAgg) {
    const int lane = threadIdx.x & 63;
    int gw = (blockIdx.x * blockDim.x + threadIdx.x) >> 6;
    const int nw = (gridDim.x * blockDim.x) >> 6;
    const int EE = E + N;
    for (int e = gw; e < EE; e += nw) {
        int s, d;
        if (e < E) { s = ei[e]; d = ei[E + e]; }
        else       { s = d = e - E; }
        float alpha = ex[e] / denom[d];
        unsafeAtomicAdd(&OutAgg[(size_t)d * 64 + lane], H[(size_t)s * 64 + lane] * alpha);
    }
}

// out = relu(in + bias[j])
__global__ void bias_relu_kernel(const float* __restrict__ In, const float* __restrict__ b,
                                 float* __restrict__ Out, int total) {
    int idx = blockIdx.x * blockDim.x + threadIdx.x;
    const int stride = gridDim.x * blockDim.x;
    for (; idx < total; idx += stride) {
        float v = In[idx] + b[idx & 63];
        Out[idx] = v > 0.f ? v : 0.f;
    }
}

// global mean pool accumulation: one wave per node
__global__ void pool_kernel(const float* __restrict__ H, const int* __restrict__ batch,
                            float* __restrict__ sums, int* __restrict__ cnts, int N) {
    const int lane = threadIdx.x & 63;
    int gw = (blockIdx.x * blockDim.x + threadIdx.x) >> 6;
    const int nw = (gridDim.x * blockDim.x) >> 6;
    for (int n = gw; n < N; n += nw) {
        int b = batch[n];
        unsafeAtomicAdd(&sums[(size_t)b * 64 + lane], H[(size_t)n * 64 + lane]);
        if (lane == 0) atomicAdd(&cnts[b], 1);
    }
}

// final MLP + log_softmax, one block (64 threads) per graph
__global__ void mlp_kernel(const float* __restrict__ sums, const int* __restrict__ cnts,
                           const float* __restrict__ b2,
                           const float* __restrict__ lw, const float* __restrict__ lb,
                           const float* __restrict__ cw, const float* __restrict__ cb,
                           float* __restrict__ out) {
    __shared__ float gv[64];
    __shared__ float z[32];
    __shared__ float logits[6];
    const int g = blockIdx.x;
    const int t = threadIdx.x;

    float cnt = (float)cnts[g];
    cnt = cnt > 1.f ? cnt : 1.f;
    gv[t] = sums[(size_t)g * 64 + t] / cnt + b2[t];
    __syncthreads();

    if (t < 32) {
        float acc = lb[t];
#pragma unroll
        for (int k = 0; k < 64; k++) acc += gv[k] * lw[k * 32 + t];
        z[t] = acc > 0.f ? acc : 0.f;
    }
    __syncthreads();
    if (t < 6) {
        float acc = cb[t];
#pragma unroll
        for (int k = 0; k < 32; k++) acc += z[k] * cw[k * 6 + t];
        logits[t] = acc;
    }
    __syncthreads();
    if (t == 0) {
        float m = logits[0];
#pragma unroll
        for (int i = 1; i < 6; i++) m = fmaxf(m, logits[i]);
        float s = 0.f;
#pragma unroll
        for (int i = 0; i < 6; i++) s += expf(logits[i] - m);
        float lse = m + logf(s);
#pragma unroll
        for (int i = 0; i < 6; i++) out[(size_t)g * 6 + i] = logits[i] - lse;
    }
}

// ---------------- launch ----------------

extern "C" void kernel_launch(void* const* d_in, const int* in_sizes, int n_in,
                              void* d_out, int out_size, void* d_ws, size_t ws_size,
                              hipStream_t stream) {
    const float* x    = (const float*)d_in[0];
    const int*   ei   = (const int*)d_in[1];
    const int*   batch= (const int*)d_in[2];
    const float* W1   = (const float*)d_in[3];
    const float* as1  = (const float*)d_in[4];
    const float* ad1  = (const float*)d_in[5];
    const float* b1   = (const float*)d_in[6];
    const float* W2   = (const float*)d_in[7];
    const float* as2  = (const float*)d_in[8];
    const float* ad2  = (const float*)d_in[9];
    const float* b2   = (const float*)d_in[10];
    const float* lw   = (const float*)d_in[11];
    const float* lb   = (const float*)d_in[12];
    const float* cw   = (const float*)d_in[13];
    const float* cb   = (const float*)d_in[14];
    float* out = (float*)d_out;

    const int N  = in_sizes[0] / 128;
    const int E  = in_sizes[1] / 2;
    const int G  = out_size / 6;
    const int EE = E + N;

    char* ws = (char*)d_ws;
    size_t off = 0;
    auto alloc = [&](size_t bytes) {
        void* p = ws + off;
        off += (bytes + 255) & ~size_t(255);
        return p;
    };
    float*    hA    = (float*)alloc((size_t)N * 64 * 4);
    float*    hB    = (float*)alloc((size_t)N * 64 * 4);
    float*    sc_s  = (float*)alloc((size_t)N * 4);
    float*    sc_d  = (float*)alloc((size_t)N * 4);
    unsigned* emax  = (unsigned*)alloc((size_t)N * 4);
    float*    denom = (float*)alloc((size_t)N * 4);
    float*    exbuf = (float*)alloc((size_t)EE * 4);
    float*    psum  = (float*)alloc((size_t)G * 64 * 4);
    int*      pcnt  = (int*)alloc((size_t)G * 4);
    (void)ws_size;

    const int TB = 256;

    // ---- layer 1 ----
    gat_gemm_kernel<128><<<1024, TB, 0, stream>>>(x, W1, as1, ad1, hA, sc_s, sc_d, N);
    hipMemsetAsync(emax, 0, (size_t)N * 4, stream);
    hipMemsetAsync(denom, 0, (size_t)N * 4, stream);
    hipMemsetAsync(hB, 0, (size_t)N * 64 * 4, stream);
    edge_max_kernel<<<4096, TB, 0, stream>>>(ei, E, N, sc_s, sc_d, exbuf, emax);
    edge_exp_kernel<<<4096, TB, 0, stream>>>(ei, E, N, exbuf, emax, denom);
    edge_agg_kernel<<<8192, TB, 0, stream>>>(ei, E, N, exbuf, denom, hA, hB);
    bias_relu_kernel<<<4096, TB, 0, stream>>>(hB, b1, hA, N * 64);

    // ---- layer 2 ----
    gat_gemm_kernel<64><<<1024, TB, 0, stream>>>(hA, W2, as2, ad2, hB, sc_s, sc_d, N);
    hipMemsetAsync(emax, 0, (size_t)N * 4, stream);
    hipMemsetAsync(denom, 0, (size_t)N * 4, stream);
    hipMemsetAsync(hA, 0, (size_t)N * 64 * 4, stream);
    edge_max_kernel<<<4096, TB, 0, stream>>>(ei, E, N, sc_s, sc_d, exbuf, emax);
    edge_exp_kernel<<<4096, TB, 0, stream>>>(ei, E, N, exbuf, emax, denom);
    edge_agg_kernel<<<8192, TB, 0, stream>>>(ei, E, N, exbuf, denom, hB, hA);

    // ---- pooling + MLP head ----
    hipMemsetAsync(psum, 0, (size_t)G * 64 * 4, stream);
    hipMemsetAsync(pcnt, 0, (size_t)G * 4, stream);
    pool_kernel<<<4096, TB, 0, stream>>>(hA, batch, psum, pcnt, N);
    mlp_kernel<<<G, 64, 0, stream>>>(psum, pcnt, b2, lw, lb, cw, cb, out);
}

// Round 2
// 1177.945 us; speedup vs baseline: 2.0328x; 2.0328x over previous
//
#include <hip/hip_runtime.h>

// ---------------- node GEMM + attention scores ----------------
// H[r][j] = sum_k X[r][k] * W[k][j];  sc_s[r] = H[r].a_s;  sc_d[r] = H[r].a_d
template<int K>
__global__ void gat_gemm_kernel(const float* __restrict__ X, const float* __restrict__ W,
                                const float* __restrict__ a_s, const float* __restrict__ a_d,
                                float* __restrict__ H, float* __restrict__ sc_s,
                                float* __restrict__ sc_d, int nrows) {
    __shared__ float Wl[K * 64];
    __shared__ float As[64];
    __shared__ float Ad[64];
    for (int i = threadIdx.x; i < K * 64; i += blockDim.x) Wl[i] = W[i];
    if (threadIdx.x < 64) {
        As[threadIdx.x] = a_s[threadIdx.x];
        Ad[threadIdx.x] = a_d[threadIdx.x];
    }
    __syncthreads();

    const int lane = threadIdx.x & 63;
    const int wave = threadIdx.x >> 6;
    const int wpb  = blockDim.x >> 6;
    const int gw   = blockIdx.x * wpb + wave;
    const int nw   = gridDim.x * wpb;

    for (int r = gw; r < nrows; r += nw) {
        const float* xr = X + (size_t)r * K;
        float acc = 0.f;
#pragma unroll
        for (int k = 0; k < K; k += 4) {
            float4 xv = *reinterpret_cast<const float4*>(xr + k);
            acc += xv.x * Wl[(k + 0) * 64 + lane];
            acc += xv.y * Wl[(k + 1) * 64 + lane];
            acc += xv.z * Wl[(k + 2) * 64 + lane];
            acc += xv.w * Wl[(k + 3) * 64 + lane];
        }
        H[(size_t)r * 64 + lane] = acc;
        float ps = acc * As[lane];
        float pd = acc * Ad[lane];
#pragma unroll
        for (int off = 32; off; off >>= 1) {
            ps += __shfl_down(ps, off);
            pd += __shfl_down(pd, off);
        }
        if (lane == 0) {
            sc_s[r] = ps;
            sc_d[r] = pd;
        }
    }
}

// ---------------- CSR build (once per launch; reused by both layers) ----------------

__global__ void hist_kernel(const int* __restrict__ dst, int* __restrict__ cnt, int E) {
    int idx = blockIdx.x * blockDim.x + threadIdx.x;
    const int stride = gridDim.x * blockDim.x;
    for (; idx < E; idx += stride) atomicAdd(&cnt[dst[idx]], 1);
}

// single-block exclusive scan of cnt[0..N-1] -> rowptr[0..N]
__global__ void scan_kernel(const int* __restrict__ cnt, int* __restrict__ rowptr, int N) {
    const int T = 1024;
    __shared__ int sums[T];
    const int t = threadIdx.x;
    const int chunk = (N + T - 1) / T;
    const int lo = t * chunk;
    const int hi = min(lo + chunk, N);
    int s = 0;
    for (int i = lo; i < hi; i++) s += cnt[i];
    sums[t] = s;
    __syncthreads();
    // Hillis-Steele inclusive scan over sums
    for (int off = 1; off < T; off <<= 1) {
        int u = (t >= off) ? sums[t - off] : 0;
        __syncthreads();
        sums[t] += u;
        __syncthreads();
    }
    int run = sums[t] - s;  // exclusive offset for this thread's chunk
    for (int i = lo; i < hi; i++) {
        rowptr[i] = run;
        run += cnt[i];
    }
    if (hi == N) rowptr[N] = run;
}

__global__ void scatter_kernel(const int* __restrict__ ei, const int* __restrict__ rowptr,
                               int* __restrict__ cursor, int* __restrict__ col, int E) {
    int idx = blockIdx.x * blockDim.x + threadIdx.x;
    const int stride = gridDim.x * blockDim.x;
    for (; idx < E; idx += stride) {
        int d = ei[E + idx];
        int pos = rowptr[d] + atomicAdd(&cursor[d], 1);
        col[pos] = ei[idx];
    }
}

// ---------------- fused per-node online-softmax aggregation ----------------
// One wave per dst node: self-loop seeds the state, then walk incoming edges.
// out[i][lane] = (sum_j exp(e_j - m) * H[src_j][lane]) / denom + bias[lane]  (opt. relu)
template<bool RELU>
__global__ void gat_fused_agg(const int* __restrict__ rowptr, const int* __restrict__ col,
                              const float* __restrict__ sc_s, const float* __restrict__ sc_d,
                              const float* __restrict__ H, const float* __restrict__ bias,
                              float* __restrict__ Out, int N) {
    const int lane = threadIdx.x & 63;
    int gw = (blockIdx.x * blockDim.x + threadIdx.x) >> 6;
    const int nw = (gridDim.x * blockDim.x) >> 6;
    const float bl = bias[lane];
    for (int i = gw; i < N; i += nw) {
        const float scd = sc_d[i];
        float es = sc_s[i] + scd;
        es = es > 0.f ? es : 0.2f * es;   // self loop
        float m = es;
        float denom = 1.f;
        float acc = H[(size_t)i * 64 + lane];
        const int jb = rowptr[i], je = rowptr[i + 1];
        int j = jb;
        for (; j + 4 <= je; j += 4) {
            const int s0 = col[j], s1 = col[j + 1], s2 = col[j + 2], s3 = col[j + 3];
            float e0 = sc_s[s0] + scd;
            float e1 = sc_s[s1] + scd;
            float e2 = sc_s[s2] + scd;
            float e3 = sc_s[s3] + scd;
            e0 = e0 > 0.f ? e0 : 0.2f * e0;
            e1 = e1 > 0.f ? e1 : 0.2f * e1;
            e2 = e2 > 0.f ? e2 : 0.2f * e2;
            e3 = e3 > 0.f ? e3 : 0.2f * e3;
            const float h0 = H[(size_t)s0 * 64 + lane];
            const float h1 = H[(size_t)s1 * 64 + lane];
            const float h2 = H[(size_t)s2 * 64 + lane];
            const float h3 = H[(size_t)s3 * 64 + lane];
            const float mn = fmaxf(fmaxf(fmaxf(e0, e1), fmaxf(e2, e3)), m);
            const float scale = __expf(m - mn);
            const float w0 = __expf(e0 - mn);
            const float w1 = __expf(e1 - mn);
            const float w2 = __expf(e2 - mn);
            const float w3 = __expf(e3 - mn);
            denom = denom * scale + ((w0 + w1) + (w2 + w3));
            acc = acc * scale + w0 * h0 + w1 * h1 + w2 * h2 + w3 * h3;
            m = mn;
        }
        for (; j < je; j++) {
            const int s0 = col[j];
            float e0 = sc_s[s0] + scd;
            e0 = e0 > 0.f ? e0 : 0.2f * e0;
            const float h0 = H[(size_t)s0 * 64 + lane];
            const float mn = fmaxf(e0, m);
            const float scale = __expf(m - mn);
            const float w0 = __expf(e0 - mn);
            denom = denom * scale + w0;
            acc = acc * scale + w0 * h0;
            m = mn;
        }
        float o = acc / denom + bl;
        if (RELU) o = o > 0.f ? o : 0.f;
        Out[(size_t)i * 64 + lane] = o;
    }
}

// ---------------- pooling + head ----------------

__global__ void pool_kernel(const float* __restrict__ H, const int* __restrict__ batch,
                            float* __restrict__ sums, int* __restrict__ cnts, int N) {
    const int lane = threadIdx.x & 63;
    int gw = (blockIdx.x * blockDim.x + threadIdx.x) >> 6;
    const int nw = (gridDim.x * blockDim.x) >> 6;
    for (int n = gw; n < N; n += nw) {
        int b = batch[n];
        unsafeAtomicAdd(&sums[(size_t)b * 64 + lane], H[(size_t)n * 64 + lane]);
        if (lane == 0) atomicAdd(&cnts[b], 1);
    }
}

// final MLP + log_softmax, one block (64 threads) per graph; b2 already added upstream
__global__ void mlp_kernel(const float* __restrict__ sums, const int* __restrict__ cnts,
                           const float* __restrict__ lw, const float* __restrict__ lb,
                           const float* __restrict__ cw, const float* __restrict__ cb,
                           float* __restrict__ out) {
    __shared__ float gv[64];
    __shared__ float z[32];
    __shared__ float logits[6];
    const int g = blockIdx.x;
    const int t = threadIdx.x;

    float cnt = (float)cnts[g];
    cnt = cnt > 1.f ? cnt : 1.f;
    gv[t] = sums[(size_t)g * 64 + t] / cnt;
    __syncthreads();

    if (t < 32) {
        float acc = lb[t];
#pragma unroll
        for (int k = 0; k < 64; k++) acc += gv[k] * lw[k * 32 + t];
        z[t] = acc > 0.f ? acc : 0.f;
    }
    __syncthreads();
    if (t < 6) {
        float acc = cb[t];
#pragma unroll
        for (int k = 0; k < 32; k++) acc += z[k] * cw[k * 6 + t];
        logits[t] = acc;
    }
    __syncthreads();
    if (t == 0) {
        float m = logits[0];
#pragma unroll
        for (int i = 1; i < 6; i++) m = fmaxf(m, logits[i]);
        float s = 0.f;
#pragma unroll
        for (int i = 0; i < 6; i++) s += expf(logits[i] - m);
        float lse = m + logf(s);
#pragma unroll
        for (int i = 0; i < 6; i++) out[(size_t)g * 6 + i] = logits[i] - lse;
    }
}

// ---------------- launch ----------------

extern "C" void kernel_launch(void* const* d_in, const int* in_sizes, int n_in,
                              void* d_out, int out_size, void* d_ws, size_t ws_size,
                              hipStream_t stream) {
    const float* x    = (const float*)d_in[0];
    const int*   ei   = (const int*)d_in[1];
    const int*   batch= (const int*)d_in[2];
    const float* W1   = (const float*)d_in[3];
    const float* as1  = (const float*)d_in[4];
    const float* ad1  = (const float*)d_in[5];
    const float* b1   = (const float*)d_in[6];
    const float* W2   = (const float*)d_in[7];
    const float* as2  = (const float*)d_in[8];
    const float* ad2  = (const float*)d_in[9];
    const float* b2   = (const float*)d_in[10];
    const float* lw   = (const float*)d_in[11];
    const float* lb   = (const float*)d_in[12];
    const float* cw   = (const float*)d_in[13];
    const float* cb   = (const float*)d_in[14];
    float* out = (float*)d_out;

    const int N  = in_sizes[0] / 128;
    const int E  = in_sizes[1] / 2;
    const int G  = out_size / 6;

    char* ws = (char*)d_ws;
    size_t off = 0;
    auto alloc = [&](size_t bytes) {
        void* p = ws + off;
        off += (bytes + 255) & ~size_t(255);
        return p;
    };
    float* hA     = (float*)alloc((size_t)N * 64 * 4);
    float* hB     = (float*)alloc((size_t)N * 64 * 4);
    float* sc_s   = (float*)alloc((size_t)N * 4);
    float* sc_d   = (float*)alloc((size_t)N * 4);
    int*   cnt    = (int*)alloc((size_t)N * 4);
    int*   cursor = (int*)alloc((size_t)N * 4);
    int*   rowptr = (int*)alloc((size_t)(N + 1) * 4);
    int*   colidx = (int*)alloc((size_t)E * 4);
    float* psum   = (float*)alloc((size_t)G * 64 * 4);
    int*   pcnt   = (int*)alloc((size_t)G * 4);
    (void)ws_size;

    const int TB = 256;

    // ---- CSR build by dst (self loops handled inline in fused kernel) ----
    hipMemsetAsync(cnt, 0, (size_t)N * 4, stream);
    hipMemsetAsync(cursor, 0, (size_t)N * 4, stream);
    hist_kernel<<<2048, TB, 0, stream>>>(ei + E, cnt, E);
    scan_kernel<<<1, 1024, 0, stream>>>(cnt, rowptr, N);
    scatter_kernel<<<2048, TB, 0, stream>>>(ei, rowptr, cursor, colidx, E);

    // ---- layer 1 ----
    gat_gemm_kernel<128><<<1024, TB, 0, stream>>>(x, W1, as1, ad1, hA, sc_s, sc_d, N);
    gat_fused_agg<true><<<2048, TB, 0, stream>>>(rowptr, colidx, sc_s, sc_d, hA, b1, hB, N);

    // ---- layer 2 ----
    gat_gemm_kernel<64><<<1024, TB, 0, stream>>>(hB, W2, as2, ad2, hA, sc_s, sc_d, N);
    gat_fused_agg<false><<<2048, TB, 0, stream>>>(rowptr, colidx, sc_s, sc_d, hA, b2, hB, N);

    // ---- pooling + MLP head ----
    hipMemsetAsync(psum, 0, (size_t)G * 64 * 4, stream);
    hipMemsetAsync(pcnt, 0, (size_t)G * 4, stream);
    pool_kernel<<<2048, TB, 0, stream>>>(hB, batch, psum, pcnt, N);
    mlp_kernel<<<G, 64, 0, stream>>>(psum, pcnt, lw, lb, cw, cb, out);
}